// Round 8
// baseline (341.111 us; speedup 1.0000x reference)
//
#include <hip/hip_runtime.h>
#include <hip/hip_bf16.h>
#include <hip/hip_fp16.h>
#include <math.h>

#define BATCH   4
#define SEQ     1024
#define DMODEL  2048
#define NHEADS  16
#define NGROUPS 2
#define HDIM    128
#define ROWS    (BATCH * SEQ)      // 4096
#define NQKV    2560               // 2048 q + 256 k + 256 v

typedef float    f32x4 __attribute__((ext_vector_type(4)));
typedef _Float16 f16x8 __attribute__((ext_vector_type(8)));

__device__ __forceinline__ void glds16(const void* g, void* s) {
    __builtin_amdgcn_global_load_lds(
        (__attribute__((address_space(1))) void*)g,
        (__attribute__((address_space(3))) void*)s, 16, 0, 0);
}

// 16-lane (row) reductions via DPP — pure VALU, no LDS-pipe ds_swizzle.
__device__ __forceinline__ float red16_max(float v) {
    v = fmaxf(v, __int_as_float(__builtin_amdgcn_mov_dpp(__float_as_int(v), 0xB1, 0xF, 0xF, true)));  // quad xor1
    v = fmaxf(v, __int_as_float(__builtin_amdgcn_mov_dpp(__float_as_int(v), 0x4E, 0xF, 0xF, true)));  // quad xor2
    v = fmaxf(v, __int_as_float(__builtin_amdgcn_mov_dpp(__float_as_int(v), 0x124, 0xF, 0xF, true))); // row_ror:4
    v = fmaxf(v, __int_as_float(__builtin_amdgcn_mov_dpp(__float_as_int(v), 0x128, 0xF, 0xF, true))); // row_ror:8
    return v;
}
__device__ __forceinline__ float red16_sum(float v) {
    v += __int_as_float(__builtin_amdgcn_mov_dpp(__float_as_int(v), 0xB1, 0xF, 0xF, true));
    v += __int_as_float(__builtin_amdgcn_mov_dpp(__float_as_int(v), 0x4E, 0xF, 0xF, true));
    v += __int_as_float(__builtin_amdgcn_mov_dpp(__float_as_int(v), 0x124, 0xF, 0xF, true));
    v += __int_as_float(__builtin_amdgcn_mov_dpp(__float_as_int(v), 0x128, 0xF, 0xF, true));
    return v;
}

// ---------------------------------------------------------------------------
// Fused: RoPE tables (blocks 0..255) + bias concat (blocks 256..265).
// ---------------------------------------------------------------------------
__global__ void prep_const_kernel(float* __restrict__ sin_t, float* __restrict__ cos_t,
                                  const float* __restrict__ bq, const float* __restrict__ bk,
                                  const float* __restrict__ bv, float* __restrict__ bc) {
    int bid = blockIdx.x;
    if (bid < 256) {
        int idx = bid * 256 + threadIdx.x;
        int p = idx >> 6, j = idx & 63;
        float inv = powf(10000.0f, -(float)j * (1.0f / 64.0f));
        float f = (float)p * inv;
        sin_t[idx] = sinf(f);
        cos_t[idx] = cosf(f);
    } else {
        int i = (bid - 256) * 256 + threadIdx.x;
        if (i < NQKV)
            bc[i] = (i < 2048) ? bq[i] : ((i < 2304) ? bk[i - 2048] : bv[i - 2304]);
    }
}

// ---------------------------------------------------------------------------
// Convert x fp32 -> fp16, 8 elems/thread.
// ---------------------------------------------------------------------------
__global__ void convert_x_kernel(const float* __restrict__ x, _Float16* __restrict__ xo) {
    int i = (blockIdx.x * 256 + threadIdx.x) * 8;
    float v[8];
    *reinterpret_cast<float4*>(&v[0]) = *reinterpret_cast<const float4*>(x + i);
    *reinterpret_cast<float4*>(&v[4]) = *reinterpret_cast<const float4*>(x + i + 4);
    f16x8 h;
#pragma unroll
    for (int j = 0; j < 8; ++j) h[j] = (_Float16)v[j];
    *reinterpret_cast<f16x8*>(xo + i) = h;
}

// ---------------------------------------------------------------------------
// All four W transposes in one launch. Grid (72, 32):
//  x<32: Wq -> wqkv row 0 | x<36: Wk -> row 2048 | x<40: Wv -> row 2304 | else Wo.
// ---------------------------------------------------------------------------
__global__ __launch_bounds__(256)
void transpose_w_all_kernel(const float* __restrict__ Wq, const float* __restrict__ Wk,
                            const float* __restrict__ Wv, const float* __restrict__ Wo,
                            _Float16* __restrict__ wqkv, _Float16* __restrict__ wot) {
    __shared__ float tile[64][65];
    int bx = blockIdx.x;
    const float* W; int ldw, drow0, nb; _Float16* dst;
    if (bx < 32)      { W = Wq; ldw = DMODEL; dst = wqkv; drow0 = 0;    nb = bx; }
    else if (bx < 36) { W = Wk; ldw = 256;    dst = wqkv; drow0 = 2048; nb = bx - 32; }
    else if (bx < 40) { W = Wv; ldw = 256;    dst = wqkv; drow0 = 2304; nb = bx - 36; }
    else              { W = Wo; ldw = DMODEL; dst = wot;  drow0 = 0;    nb = bx - 40; }
    int n0 = nb * 64, k0 = blockIdx.y * 64;
#pragma unroll
    for (int it = 0; it < 16; ++it) {
        int e = it * 256 + threadIdx.x;
        int r = e >> 6, c = e & 63;
        tile[r][c] = W[(size_t)(k0 + r) * ldw + n0 + c];
    }
    __syncthreads();
#pragma unroll
    for (int it = 0; it < 16; ++it) {
        int e = it * 256 + threadIdx.x;
        int nr = e >> 6, kc = e & 63;
        dst[(size_t)(drow0 + n0 + nr) * DMODEL + k0 + kc] = (_Float16)tile[kc][nr];
    }
}

// ---------------------------------------------------------------------------
// fp16 GEMM: C[M][N] = A[M][K] @ Bt^T[N][K] + bias.  (unchanged)
// ---------------------------------------------------------------------------
template<int OUT_HALF>
__global__ __launch_bounds__(256, 3)
void gemm_fp16_kernel(const _Float16* __restrict__ A, const _Float16* __restrict__ Bt,
                      const float* __restrict__ bias, void* __restrict__ Cout,
                      int M, int N, int K) {
    __shared__ __align__(16) _Float16 lds[16384];   // 32 KB: A [128][64], B [128][64]
    _Float16* As = lds;
    _Float16* Bs = lds + 8192;

    const int tid  = threadIdx.x;
    const int lane = tid & 63;
    const int w    = tid >> 6;
    const int nbn  = N >> 7;
    const int nwg  = gridDim.x;
    const int cpx  = nwg >> 3;
    const int bid  = blockIdx.x;
    const int swz  = (bid & 7) * cpx + (bid >> 3);
    const int row0 = (swz / nbn) << 7;
    const int col0 = (swz % nbn) << 7;
    const int wr   = (w >> 1) << 6;
    const int wc   = (w & 1) << 6;

    const f32x4 fz = {0.f, 0.f, 0.f, 0.f};
    f32x4 acc[4][4];
#pragma unroll
    for (int i = 0; i < 4; ++i)
#pragma unroll
        for (int j = 0; j < 4; ++j) acc[i][j] = fz;

    for (int k0 = 0; k0 < K; k0 += 64) {
        __syncthreads();
#pragma unroll
        for (int it = 0; it < 4; ++it) {
            int chunk = it * 256 + tid;
            int trow  = chunk >> 3;
            int jp    = chunk & 7;
            int j     = jp ^ (trow & 7);
            size_t aoff = (size_t)(row0 + trow) * K + k0 + j * 8;
            size_t boff = (size_t)(col0 + trow) * K + k0 + j * 8;
            int ldst = (it * 256 + (tid & 192)) * 16;
            glds16(A  + aoff, (char*)As + ldst);
            glds16(Bt + boff, (char*)Bs + ldst);
        }
        __syncthreads();

#pragma unroll
        for (int ks = 0; ks < 2; ++ks) {
            f16x8 a4[4], b4[4];
            int ja = ks * 4 + (lane >> 4);
#pragma unroll
            for (int i = 0; i < 4; ++i) {
                int ar = wr + i * 16 + (lane & 15);
                a4[i] = *reinterpret_cast<const f16x8*>(
                    (const char*)As + ar * 128 + ((ja ^ (ar & 7)) << 4));
                int br = wc + i * 16 + (lane & 15);
                b4[i] = *reinterpret_cast<const f16x8*>(
                    (const char*)Bs + br * 128 + ((ja ^ (br & 7)) << 4));
            }
#pragma unroll
            for (int i = 0; i < 4; ++i)
#pragma unroll
                for (int j = 0; j < 4; ++j)
                    acc[i][j] = __builtin_amdgcn_mfma_f32_16x16x32_f16(a4[i], b4[j], acc[i][j], 0, 0, 0);
        }
    }

    float bv4[4];
#pragma unroll
    for (int j = 0; j < 4; ++j) bv4[j] = bias[col0 + wc + j * 16 + (lane & 15)];
#pragma unroll
    for (int i = 0; i < 4; ++i)
#pragma unroll
        for (int j = 0; j < 4; ++j)
#pragma unroll
            for (int r = 0; r < 4; ++r) {
                int grow = row0 + wr + i * 16 + ((lane >> 4) << 2) + r;
                int gcol = col0 + wc + j * 16 + (lane & 15);
                float v = acc[i][j][r] + bv4[j];
                if (OUT_HALF)
                    ((_Float16*)Cout)[(size_t)grow * N + gcol] = (_Float16)v;
                else
                    ((float*)Cout)[(size_t)grow * N + gcol] = v;
            }
}

// ---------------------------------------------------------------------------
// Fused K-RoPE + V-transpose. Grid (SEQ/64, BATCH*NGROUPS), 256 thr.
// kh: [B][G][S][D];  vt: [B][G][D][S].
// ---------------------------------------------------------------------------
__global__ __launch_bounds__(256)
void prep_kv_kernel(const _Float16* __restrict__ qkv,
                    const float* __restrict__ sin_t, const float* __restrict__ cos_t,
                    _Float16* __restrict__ kh, _Float16* __restrict__ vt) {
    __shared__ _Float16 tile[64][72];
    int s0 = blockIdx.x * 64, bg = blockIdx.y;
    int b = bg >> 1, g = bg & 1;

    // ---- RoPE on K slab (64 rows x 128) ----
#pragma unroll
    for (int it = 0; it < 2; ++it) {
        int u = it * 256 + threadIdx.x;     // 0..511
        int r = u >> 3, jc = u & 7;
        int s = s0 + r;
        int j0 = jc * 8;
        const _Float16* src = qkv + (size_t)(b * SEQ + s) * NQKV + 2048 + g * HDIM;
        _Float16* dst = kh + ((size_t)bg * SEQ + s) * HDIM;
        f16x8 x1 = *reinterpret_cast<const f16x8*>(src + j0);
        f16x8 x2 = *reinterpret_cast<const f16x8*>(src + j0 + 64);
        float cc[8], ss[8];
        *reinterpret_cast<float4*>(&cc[0]) = *reinterpret_cast<const float4*>(cos_t + s * 64 + j0);
        *reinterpret_cast<float4*>(&cc[4]) = *reinterpret_cast<const float4*>(cos_t + s * 64 + j0 + 4);
        *reinterpret_cast<float4*>(&ss[0]) = *reinterpret_cast<const float4*>(sin_t + s * 64 + j0);
        *reinterpret_cast<float4*>(&ss[4]) = *reinterpret_cast<const float4*>(sin_t + s * 64 + j0 + 4);
        f16x8 o1, o2;
#pragma unroll
        for (int j = 0; j < 8; ++j) {
            float f1 = (float)x1[j], f2 = (float)x2[j];
            o1[j] = (_Float16)(f1 * cc[j] - f2 * ss[j]);
            o2[j] = (_Float16)(f2 * cc[j] + f1 * ss[j]);
        }
        *reinterpret_cast<f16x8*>(dst + j0)      = o1;
        *reinterpret_cast<f16x8*>(dst + j0 + 64) = o2;
    }

    // ---- transpose V slab (two 64-d halves through one LDS tile) ----
#pragma unroll
    for (int half = 0; half < 2; ++half) {
        int d0 = half * 64;
        __syncthreads();
#pragma unroll
        for (int it = 0; it < 2; ++it) {
            int c = it * 256 + threadIdx.x;
            int r = c >> 3, cc = (c & 7) * 8;
            f16x8 v = *reinterpret_cast<const f16x8*>(
                qkv + (size_t)(b * SEQ + s0 + r) * NQKV + 2304 + g * HDIM + d0 + cc);
#pragma unroll
            for (int j = 0; j < 8; ++j) tile[r][cc + j] = v[j];
        }
        __syncthreads();
#pragma unroll
        for (int it = 0; it < 2; ++it) {
            int c = it * 256 + threadIdx.x;
            int dr = c >> 3, sc = (c & 7) * 8;
            f16x8 o;
#pragma unroll
            for (int j = 0; j < 8; ++j) o[j] = tile[sc + j][dr];
            *reinterpret_cast<f16x8*>(vt + ((size_t)bg * HDIM + d0 + dr) * SEQ + s0 + sc) = o;
        }
    }
}

// ---------------------------------------------------------------------------
// Flash attention, fp16 MFMA. Grid (SEQ/128, NHEADS, BATCH), 256 thr (4 waves),
// 3 blocks/CU (48 KB LDS, single-buffered K/V — TLP hides staging latency).
// Wave owns 32 q-rows (K/V fragment reuse). Softmax in exp2 domain (log2e
// folded into Q scale); l-reduction deferred to epilogue; DPP row reduces.
// ---------------------------------------------------------------------------
__global__ __launch_bounds__(256, 3)
void attn_kernel(const _Float16* __restrict__ qkv, const _Float16* __restrict__ kh,
                 const _Float16* __restrict__ vt,
                 const float* __restrict__ sin_t, const float* __restrict__ cos_t,
                 _Float16* __restrict__ ao) {
    __shared__ __align__(16) char smem[49152];
    // [0,16K) K | [16K,32K) V | [32K,48K) P (4 KB per wave)

    const int tid = threadIdx.x, lane = tid & 63, w = tid >> 6;
    const int qt0 = blockIdx.x << 7;            // 128 q rows per block
    const int h = blockIdx.y, b = blockIdx.z;
    const int g = h >> 3;
    const _Float16* kbase = kh + (size_t)(b * NGROUPS + g) * SEQ * HDIM;
    const _Float16* vbase = vt + (size_t)(b * NGROUPS + g) * HDIM * SEQ;
    char* Kb = smem;
    char* Vb = smem + 16384;
    char* Pw = smem + 32768 + w * 4096;         // [32 rows][128 B]

    // ---- Q fragments (two 16-row halves) + in-register RoPE ----
    // Scale folds 1/sqrt(128) * log2(e): softmax runs in exp2 domain.
    const int sl = lane >> 4;
    f16x8 af[2][4];
#pragma unroll
    for (int m = 0; m < 2; ++m) {
        int srow = qt0 + w * 32 + m * 16 + (lane & 15);
        const _Float16* qrp = qkv + (size_t)(b * SEQ + srow) * NQKV + h * HDIM;
#pragma unroll
        for (int ks = 0; ks < 4; ++ks)
            af[m][ks] = *reinterpret_cast<const f16x8*>(qrp + (ks * 4 + sl) * 8);
        const float qsc = 0.12751741f;          // 2^-3.5 * log2(e)
#pragma unroll
        for (int ks = 0; ks < 2; ++ks) {
            int d0 = (ks * 4 + sl) * 8;
            float cc[8], ss[8];
            *reinterpret_cast<float4*>(&cc[0]) = *reinterpret_cast<const float4*>(cos_t + srow * 64 + d0);
            *reinterpret_cast<float4*>(&cc[4]) = *reinterpret_cast<const float4*>(cos_t + srow * 64 + d0 + 4);
            *reinterpret_cast<float4*>(&ss[0]) = *reinterpret_cast<const float4*>(sin_t + srow * 64 + d0);
            *reinterpret_cast<float4*>(&ss[4]) = *reinterpret_cast<const float4*>(sin_t + srow * 64 + d0 + 4);
#pragma unroll
            for (int j = 0; j < 8; ++j) {
                float f1 = (float)af[m][ks][j], f2 = (float)af[m][ks + 2][j];
                af[m][ks][j]     = (_Float16)((f1 * cc[j] - f2 * ss[j]) * qsc);
                af[m][ks + 2][j] = (_Float16)((f2 * cc[j] + f1 * ss[j]) * qsc);
            }
        }
    }

    float m_run[2][4], l_run[2][4];
#pragma unroll
    for (int m = 0; m < 2; ++m)
#pragma unroll
        for (int r = 0; r < 4; ++r) { m_run[m][r] = -1e30f; l_run[m][r] = 0.f; }
    const f32x4 fz = {0.f, 0.f, 0.f, 0.f};
    f32x4 oacc[2][8];
#pragma unroll
    for (int m = 0; m < 2; ++m)
#pragma unroll
        for (int i = 0; i < 8; ++i) oacc[m][i] = fz;

    const int prow = lane & 15;

    for (int t = 0; t < SEQ / 64; ++t) {
        int t0 = t << 6;
#pragma unroll
        for (int it = 0; it < 4; ++it) {       // stage K tile
            int c = it * 256 + tid;
            int row = c >> 4, jc = c & 15;
            int sj = jc ^ (row & 7);
            glds16((const char*)(kbase + (size_t)(t0 + row) * HDIM) + (sj << 4),
                   Kb + (it * 256 + (tid & 192)) * 16);
        }
#pragma unroll
        for (int it = 0; it < 4; ++it) {       // stage V^T tile
            int c = it * 256 + tid;
            int d = c >> 3, jc = c & 7;
            int sj = jc ^ (d & 7);
            glds16((const char*)(vbase + (size_t)d * SEQ + t0) + (sj << 4),
                   Vb + (it * 256 + (tid & 192)) * 16);
        }
        __syncthreads();                        // drains vmcnt -> tile ready

        // ---- S = Q K^T (K fragment reused for both q-halves) ----
        f32x4 sacc[2][4];
#pragma unroll
        for (int m = 0; m < 2; ++m)
#pragma unroll
            for (int i = 0; i < 4; ++i) sacc[m][i] = fz;
#pragma unroll
        for (int ks = 0; ks < 4; ++ks) {
#pragma unroll
            for (int nf = 0; nf < 4; ++nf) {
                int trow = nf * 16 + (lane & 15);
                f16x8 bf = *reinterpret_cast<const f16x8*>(
                    Kb + trow * 256 + (((ks * 4 + (lane >> 4)) ^ (trow & 7)) << 4));
                sacc[0][nf] = __builtin_amdgcn_mfma_f32_16x16x32_f16(af[0][ks], bf, sacc[0][nf], 0, 0, 0);
                sacc[1][nf] = __builtin_amdgcn_mfma_f32_16x16x32_f16(af[1][ks], bf, sacc[1][nf], 0, 0, 0);
            }
        }

        // ---- online softmax (exp2 domain, DPP reduce, defer-max) ----
        float pm[2][4];
        float growth = -1e30f;
#pragma unroll
        for (int m = 0; m < 2; ++m)
#pragma unroll
            for (int r = 0; r < 4; ++r) {
                float v = fmaxf(fmaxf(sacc[m][0][r], sacc[m][1][r]),
                                fmaxf(sacc[m][2][r], sacc[m][3][r]));
                v = red16_max(v);
                pm[m][r] = v;
                growth = fmaxf(growth, v - m_run[m][r]);
            }
        if (__any(growth > 11.0f)) {            // 11 log2-units ~ e^7.6
            float scl[2][4];
#pragma unroll
            for (int m = 0; m < 2; ++m)
#pragma unroll
                for (int r = 0; r < 4; ++r) {
                    float mn = fmaxf(m_run[m][r], pm[m][r]);
                    scl[m][r] = __builtin_amdgcn_exp2f(m_run[m][r] - mn);
                    m_run[m][r] = mn;
                    l_run[m][r] *= scl[m][r];
                }
#pragma unroll
            for (int m = 0; m < 2; ++m)
#pragma unroll
                for (int i = 0; i < 8; ++i) {
                    f32x4 o = oacc[m][i];
                    o[0] *= scl[m][0]; o[1] *= scl[m][1];
                    o[2] *= scl[m][2]; o[3] *= scl[m][3];
                    oacc[m][i] = o;
                }
        }
#pragma unroll
        for (int m = 0; m < 2; ++m)
#pragma unroll
            for (int r = 0; r < 4; ++r) {
                float ps = 0.f;
#pragma unroll
                for (int nf = 0; nf < 4; ++nf) {
                    float p = __builtin_amdgcn_exp2f(sacc[m][nf][r] - m_run[m][r]);
                    sacc[m][nf][r] = p;
                    ps += p;
                }
                l_run[m][r] += ps;              // per-lane partial; reduced in epilogue
            }

        // ---- P -> wave-private swizzled LDS (fp16) ----
#pragma unroll
        for (int m = 0; m < 2; ++m)
#pragma unroll
            for (int nf = 0; nf < 4; ++nf)
#pragma unroll
                for (int r = 0; r < 4; ++r) {
                    int pr = m * 16 + ((lane >> 4) << 2) + r;
                    int pc = nf * 16 + (lane & 15);
                    int byte = pr * 128 + ((pc * 2) ^ ((pr & 7) << 4));
                    *reinterpret_cast<_Float16*>(Pw + byte) = (_Float16)sacc[m][nf][r];
                }

        // ---- O += P V (V fragment reused for both q-halves) ----
#pragma unroll
        for (int ks = 0; ks < 2; ++ks) {
            int chP = ks * 4 + (lane >> 4);
            f16x8 pa[2];
#pragma unroll
            for (int m = 0; m < 2; ++m)
                pa[m] = *reinterpret_cast<const f16x8*>(
                    Pw + (m * 16 + prow) * 128 + ((chP ^ (prow & 7)) << 4));
#pragma unroll
            for (int nf = 0; nf < 8; ++nf) {
                int vrow = nf * 16 + (lane & 15);
                f16x8 vf = *reinterpret_cast<const f16x8*>(
                    Vb + vrow * 128 + (((ks * 4 + (lane >> 4)) ^ (vrow & 7)) << 4));
                oacc[0][nf] = __builtin_amdgcn_mfma_f32_16x16x32_f16(pa[0], vf, oacc[0][nf], 0, 0, 0);
                oacc[1][nf] = __builtin_amdgcn_mfma_f32_16x16x32_f16(pa[1], vf, oacc[1][nf], 0, 0, 0);
            }
        }

        __syncthreads();                        // all waves done before restage
    }

    // ---- epilogue: reduce l, normalize, write fp16 ----
    float linv[2][4];
#pragma unroll
    for (int m = 0; m < 2; ++m)
#pragma unroll
        for (int r = 0; r < 4; ++r)
            linv[m][r] = 1.0f / red16_sum(l_run[m][r]);
#pragma unroll
    for (int m = 0; m < 2; ++m)
#pragma unroll
        for (int nf = 0; nf < 8; ++nf)
#pragma unroll
            for (int r = 0; r < 4; ++r) {
                int qr  = qt0 + w * 32 + m * 16 + ((lane >> 4) << 2) + r;
                int col = h * HDIM + nf * 16 + (lane & 15);
                float v = oacc[m][nf][r] * linv[m][r];
                ao[(size_t)(b * SEQ + qr) * DMODEL + col] = (_Float16)v;
            }
}

// ---------------------------------------------------------------------------
extern "C" void kernel_launch(void* const* d_in, const int* in_sizes, int n_in,
                              void* d_out, int out_size, void* d_ws, size_t ws_size,
                              hipStream_t stream) {
    const float* x  = (const float*)d_in[0];
    const float* Wq = (const float*)d_in[1];
    const float* bq = (const float*)d_in[2];
    const float* Wk = (const float*)d_in[3];
    const float* bk = (const float*)d_in[4];
    const float* Wv = (const float*)d_in[5];
    const float* bv = (const float*)d_in[6];
    const float* Wo = (const float*)d_in[7];
    const float* bo = (const float*)d_in[8];
    float* out = (float*)d_out;

    char* ws = (char*)d_ws;
    _Float16* xs     = (_Float16*)(ws);                    // 16.78 MB [4096][2048]
    _Float16* wqkv16 = (_Float16*)(ws + 16777216);         // 10.49 MB [2560][2048]
    _Float16* wot16  = (_Float16*)(ws + 27262976);         //  8.39 MB [2048][2048]
    _Float16* qkv16  = (_Float16*)(ws + 35651584);         // 20.97 MB [4096][2560]
    _Float16* khb    = (_Float16*)(ws + 56623104);         //  2.10 MB [B][G][S][D]
    _Float16* vtb    = (_Float16*)(ws + 58720256);         //  2.10 MB [B][G][D][S]
    float*    sint   = (float*)(ws + 60817408);            //  0.26 MB
    float*    cost   = (float*)(ws + 61079552);            //  0.26 MB
    float*    bias_c = (float*)(ws + 61341696);            //  10 KB
    _Float16* ao = xs;   // attention output reuses xs (x dead after QKV GEMM)

    prep_const_kernel<<<266, 256, 0, stream>>>(sint, cost, bq, bk, bv, bias_c);
    convert_x_kernel<<<ROWS * DMODEL / 8 / 256, 256, 0, stream>>>(x, xs);
    transpose_w_all_kernel<<<dim3(72, 32), 256, 0, stream>>>(Wq, Wk, Wv, Wo, wqkv16, wot16);

    // QKV projection: [4096][2048] @ [2048][2560] -> fp16 [4096][2560]
    gemm_fp16_kernel<1><<<(ROWS / 128) * (NQKV / 128), 256, 0, stream>>>(
        xs, wqkv16, bias_c, qkv16, ROWS, NQKV, DMODEL);

    prep_kv_kernel<<<dim3(SEQ / 64, BATCH * NGROUPS), 256, 0, stream>>>(
        qkv16, sint, cost, khb, vtb);

    attn_kernel<<<dim3(SEQ / 128, NHEADS, BATCH), 256, 0, stream>>>(
        qkv16, khb, vtb, sint, cost, ao);

    // Output projection: [4096][2048] @ [2048][2048] -> fp32 out
    gemm_fp16_kernel<0><<<(ROWS / 128) * (DMODEL / 128), 256, 0, stream>>>(
        ao, wot16, bo, out, ROWS, DMODEL, DMODEL);
}

// Round 9
// 266.996 us; speedup vs baseline: 1.2776x; 1.2776x over previous
//
#include <hip/hip_runtime.h>
#include <hip/hip_bf16.h>
#include <hip/hip_fp16.h>
#include <math.h>

#define BATCH   4
#define SEQ     1024
#define DMODEL  2048
#define NHEADS  16
#define NGROUPS 2
#define HDIM    128
#define ROWS    (BATCH * SEQ)      // 4096
#define NQKV    2560               // 2048 q + 256 k + 256 v

typedef float    f32x4 __attribute__((ext_vector_type(4)));
typedef _Float16 f16x8 __attribute__((ext_vector_type(8)));

__device__ __forceinline__ void glds16(const void* g, void* s) {
    __builtin_amdgcn_global_load_lds(
        (__attribute__((address_space(1))) void*)g,
        (__attribute__((address_space(3))) void*)s, 16, 0, 0);
}

// 16-lane (row) reductions via DPP — pure VALU, no LDS-pipe ds_swizzle.
__device__ __forceinline__ float red16_max(float v) {
    v = fmaxf(v, __int_as_float(__builtin_amdgcn_mov_dpp(__float_as_int(v), 0xB1, 0xF, 0xF, true)));  // quad xor1
    v = fmaxf(v, __int_as_float(__builtin_amdgcn_mov_dpp(__float_as_int(v), 0x4E, 0xF, 0xF, true)));  // quad xor2
    v = fmaxf(v, __int_as_float(__builtin_amdgcn_mov_dpp(__float_as_int(v), 0x124, 0xF, 0xF, true))); // row_ror:4
    v = fmaxf(v, __int_as_float(__builtin_amdgcn_mov_dpp(__float_as_int(v), 0x128, 0xF, 0xF, true))); // row_ror:8
    return v;
}
__device__ __forceinline__ float red16_sum(float v) {
    v += __int_as_float(__builtin_amdgcn_mov_dpp(__float_as_int(v), 0xB1, 0xF, 0xF, true));
    v += __int_as_float(__builtin_amdgcn_mov_dpp(__float_as_int(v), 0x4E, 0xF, 0xF, true));
    v += __int_as_float(__builtin_amdgcn_mov_dpp(__float_as_int(v), 0x124, 0xF, 0xF, true));
    v += __int_as_float(__builtin_amdgcn_mov_dpp(__float_as_int(v), 0x128, 0xF, 0xF, true));
    return v;
}

// ---------------------------------------------------------------------------
// Fused: RoPE tables (blocks 0..255) + bias concat (blocks 256..265).
// ---------------------------------------------------------------------------
__global__ void prep_const_kernel(float* __restrict__ sin_t, float* __restrict__ cos_t,
                                  const float* __restrict__ bq, const float* __restrict__ bk,
                                  const float* __restrict__ bv, float* __restrict__ bc) {
    int bid = blockIdx.x;
    if (bid < 256) {
        int idx = bid * 256 + threadIdx.x;
        int p = idx >> 6, j = idx & 63;
        float inv = powf(10000.0f, -(float)j * (1.0f / 64.0f));
        float f = (float)p * inv;
        sin_t[idx] = sinf(f);
        cos_t[idx] = cosf(f);
    } else {
        int i = (bid - 256) * 256 + threadIdx.x;
        if (i < NQKV)
            bc[i] = (i < 2048) ? bq[i] : ((i < 2304) ? bk[i - 2048] : bv[i - 2304]);
    }
}

// ---------------------------------------------------------------------------
// Convert x fp32 -> fp16, 8 elems/thread.
// ---------------------------------------------------------------------------
__global__ void convert_x_kernel(const float* __restrict__ x, _Float16* __restrict__ xo) {
    int i = (blockIdx.x * 256 + threadIdx.x) * 8;
    float v[8];
    *reinterpret_cast<float4*>(&v[0]) = *reinterpret_cast<const float4*>(x + i);
    *reinterpret_cast<float4*>(&v[4]) = *reinterpret_cast<const float4*>(x + i + 4);
    f16x8 h;
#pragma unroll
    for (int j = 0; j < 8; ++j) h[j] = (_Float16)v[j];
    *reinterpret_cast<f16x8*>(xo + i) = h;
}

// ---------------------------------------------------------------------------
// All four W transposes in one launch. Grid (72, 32).
// ---------------------------------------------------------------------------
__global__ __launch_bounds__(256)
void transpose_w_all_kernel(const float* __restrict__ Wq, const float* __restrict__ Wk,
                            const float* __restrict__ Wv, const float* __restrict__ Wo,
                            _Float16* __restrict__ wqkv, _Float16* __restrict__ wot) {
    __shared__ float tile[64][65];
    int bx = blockIdx.x;
    const float* W; int ldw, drow0, nb; _Float16* dst;
    if (bx < 32)      { W = Wq; ldw = DMODEL; dst = wqkv; drow0 = 0;    nb = bx; }
    else if (bx < 36) { W = Wk; ldw = 256;    dst = wqkv; drow0 = 2048; nb = bx - 32; }
    else if (bx < 40) { W = Wv; ldw = 256;    dst = wqkv; drow0 = 2304; nb = bx - 36; }
    else              { W = Wo; ldw = DMODEL; dst = wot;  drow0 = 0;    nb = bx - 40; }
    int n0 = nb * 64, k0 = blockIdx.y * 64;
#pragma unroll
    for (int it = 0; it < 16; ++it) {
        int e = it * 256 + threadIdx.x;
        int r = e >> 6, c = e & 63;
        tile[r][c] = W[(size_t)(k0 + r) * ldw + n0 + c];
    }
    __syncthreads();
#pragma unroll
    for (int it = 0; it < 16; ++it) {
        int e = it * 256 + threadIdx.x;
        int nr = e >> 6, kc = e & 63;
        dst[(size_t)(drow0 + n0 + nr) * DMODEL + k0 + kc] = (_Float16)tile[kc][nr];
    }
}

// ---------------------------------------------------------------------------
// fp16 GEMM: C[M][N] = A[M][K] @ Bt^T[N][K] + bias.  (unchanged)
// ---------------------------------------------------------------------------
template<int OUT_HALF>
__global__ __launch_bounds__(256, 3)
void gemm_fp16_kernel(const _Float16* __restrict__ A, const _Float16* __restrict__ Bt,
                      const float* __restrict__ bias, void* __restrict__ Cout,
                      int M, int N, int K) {
    __shared__ __align__(16) _Float16 lds[16384];   // 32 KB: A [128][64], B [128][64]
    _Float16* As = lds;
    _Float16* Bs = lds + 8192;

    const int tid  = threadIdx.x;
    const int lane = tid & 63;
    const int w    = tid >> 6;
    const int nbn  = N >> 7;
    const int nwg  = gridDim.x;
    const int cpx  = nwg >> 3;
    const int bid  = blockIdx.x;
    const int swz  = (bid & 7) * cpx + (bid >> 3);
    const int row0 = (swz / nbn) << 7;
    const int col0 = (swz % nbn) << 7;
    const int wr   = (w >> 1) << 6;
    const int wc   = (w & 1) << 6;

    const f32x4 fz = {0.f, 0.f, 0.f, 0.f};
    f32x4 acc[4][4];
#pragma unroll
    for (int i = 0; i < 4; ++i)
#pragma unroll
        for (int j = 0; j < 4; ++j) acc[i][j] = fz;

    for (int k0 = 0; k0 < K; k0 += 64) {
        __syncthreads();
#pragma unroll
        for (int it = 0; it < 4; ++it) {
            int chunk = it * 256 + tid;
            int trow  = chunk >> 3;
            int jp    = chunk & 7;
            int j     = jp ^ (trow & 7);
            size_t aoff = (size_t)(row0 + trow) * K + k0 + j * 8;
            size_t boff = (size_t)(col0 + trow) * K + k0 + j * 8;
            int ldst = (it * 256 + (tid & 192)) * 16;
            glds16(A  + aoff, (char*)As + ldst);
            glds16(Bt + boff, (char*)Bs + ldst);
        }
        __syncthreads();

#pragma unroll
        for (int ks = 0; ks < 2; ++ks) {
            f16x8 a4[4], b4[4];
            int ja = ks * 4 + (lane >> 4);
#pragma unroll
            for (int i = 0; i < 4; ++i) {
                int ar = wr + i * 16 + (lane & 15);
                a4[i] = *reinterpret_cast<const f16x8*>(
                    (const char*)As + ar * 128 + ((ja ^ (ar & 7)) << 4));
                int br = wc + i * 16 + (lane & 15);
                b4[i] = *reinterpret_cast<const f16x8*>(
                    (const char*)Bs + br * 128 + ((ja ^ (br & 7)) << 4));
            }
#pragma unroll
            for (int i = 0; i < 4; ++i)
#pragma unroll
                for (int j = 0; j < 4; ++j)
                    acc[i][j] = __builtin_amdgcn_mfma_f32_16x16x32_f16(a4[i], b4[j], acc[i][j], 0, 0, 0);
        }
    }

    float bv4[4];
#pragma unroll
    for (int j = 0; j < 4; ++j) bv4[j] = bias[col0 + wc + j * 16 + (lane & 15)];
#pragma unroll
    for (int i = 0; i < 4; ++i)
#pragma unroll
        for (int j = 0; j < 4; ++j)
#pragma unroll
            for (int r = 0; r < 4; ++r) {
                int grow = row0 + wr + i * 16 + ((lane >> 4) << 2) + r;
                int gcol = col0 + wc + j * 16 + (lane & 15);
                float v = acc[i][j][r] + bv4[j];
                if (OUT_HALF)
                    ((_Float16*)Cout)[(size_t)grow * N + gcol] = (_Float16)v;
                else
                    ((float*)Cout)[(size_t)grow * N + gcol] = v;
            }
}

// ---------------------------------------------------------------------------
// Fused K-RoPE + V-transpose. Grid (SEQ/64, BATCH*NGROUPS), 256 thr.
// ---------------------------------------------------------------------------
__global__ __launch_bounds__(256)
void prep_kv_kernel(const _Float16* __restrict__ qkv,
                    const float* __restrict__ sin_t, const float* __restrict__ cos_t,
                    _Float16* __restrict__ kh, _Float16* __restrict__ vt) {
    __shared__ _Float16 tile[64][72];
    int s0 = blockIdx.x * 64, bg = blockIdx.y;
    int b = bg >> 1, g = bg & 1;

#pragma unroll
    for (int it = 0; it < 2; ++it) {
        int u = it * 256 + threadIdx.x;
        int r = u >> 3, jc = u & 7;
        int s = s0 + r;
        int j0 = jc * 8;
        const _Float16* src = qkv + (size_t)(b * SEQ + s) * NQKV + 2048 + g * HDIM;
        _Float16* dst = kh + ((size_t)bg * SEQ + s) * HDIM;
        f16x8 x1 = *reinterpret_cast<const f16x8*>(src + j0);
        f16x8 x2 = *reinterpret_cast<const f16x8*>(src + j0 + 64);
        float cc[8], ss[8];
        *reinterpret_cast<float4*>(&cc[0]) = *reinterpret_cast<const float4*>(cos_t + s * 64 + j0);
        *reinterpret_cast<float4*>(&cc[4]) = *reinterpret_cast<const float4*>(cos_t + s * 64 + j0 + 4);
        *reinterpret_cast<float4*>(&ss[0]) = *reinterpret_cast<const float4*>(sin_t + s * 64 + j0);
        *reinterpret_cast<float4*>(&ss[4]) = *reinterpret_cast<const float4*>(sin_t + s * 64 + j0 + 4);
        f16x8 o1, o2;
#pragma unroll
        for (int j = 0; j < 8; ++j) {
            float f1 = (float)x1[j], f2 = (float)x2[j];
            o1[j] = (_Float16)(f1 * cc[j] - f2 * ss[j]);
            o2[j] = (_Float16)(f2 * cc[j] + f1 * ss[j]);
        }
        *reinterpret_cast<f16x8*>(dst + j0)      = o1;
        *reinterpret_cast<f16x8*>(dst + j0 + 64) = o2;
    }

#pragma unroll
    for (int half = 0; half < 2; ++half) {
        int d0 = half * 64;
        __syncthreads();
#pragma unroll
        for (int it = 0; it < 2; ++it) {
            int c = it * 256 + threadIdx.x;
            int r = c >> 3, cc = (c & 7) * 8;
            f16x8 v = *reinterpret_cast<const f16x8*>(
                qkv + (size_t)(b * SEQ + s0 + r) * NQKV + 2304 + g * HDIM + d0 + cc);
#pragma unroll
            for (int j = 0; j < 8; ++j) tile[r][cc + j] = v[j];
        }
        __syncthreads();
#pragma unroll
        for (int it = 0; it < 2; ++it) {
            int c = it * 256 + threadIdx.x;
            int dr = c >> 3, sc = (c & 7) * 8;
            f16x8 o;
#pragma unroll
            for (int j = 0; j < 8; ++j) o[j] = tile[sc + j][dr];
            *reinterpret_cast<f16x8*>(vt + ((size_t)bg * HDIM + d0 + dr) * SEQ + s0 + sc) = o;
        }
    }
}

// ---------------------------------------------------------------------------
// Flash attention, fp16 MFMA. Grid (SEQ/128, NHEADS, BATCH), 256 thr (4 waves).
// Round-7 structure: K/V double-buffered, counted vmcnt(8), raw s_barrier.
// Wave owns 32 q-rows (K/V fragment reuse). VALU diet: exp2-domain softmax
// (log2e folded into Q scale), per-lane deferred l-sum, DPP row reduces.
// ---------------------------------------------------------------------------
__global__ __launch_bounds__(256, 2)
void attn_kernel(const _Float16* __restrict__ qkv, const _Float16* __restrict__ kh,
                 const _Float16* __restrict__ vt,
                 const float* __restrict__ sin_t, const float* __restrict__ cos_t,
                 _Float16* __restrict__ ao) {
    __shared__ __align__(16) char smem[81920];
    // [0,16K) K0 | [16K,32K) V0 | [32K,48K) K1 | [48K,64K) V1 | [64K,80K) P

    const int tid = threadIdx.x, lane = tid & 63, w = tid >> 6;
    const int qt0 = blockIdx.x << 7;            // 128 q rows per block
    const int h = blockIdx.y, b = blockIdx.z;
    const int g = h >> 3;
    const _Float16* kbase = kh + (size_t)(b * NGROUPS + g) * SEQ * HDIM;
    const _Float16* vbase = vt + (size_t)(b * NGROUPS + g) * HDIM * SEQ;

    // ---- stage K/V tile 0 into buffer 0 ----
    {
        char* Kb = smem;
        char* Vb = smem + 16384;
#pragma unroll
        for (int it = 0; it < 4; ++it) {
            int c = it * 256 + tid;
            int row = c >> 4, jc = c & 15;
            int sj = jc ^ (row & 7);
            glds16((const char*)(kbase + (size_t)row * HDIM) + (sj << 4),
                   Kb + (it * 256 + (tid & 192)) * 16);
        }
#pragma unroll
        for (int it = 0; it < 4; ++it) {
            int c = it * 256 + tid;
            int d = c >> 3, jc = c & 7;
            int sj = jc ^ (d & 7);
            glds16((const char*)(vbase + (size_t)d * SEQ) + (sj << 4),
                   Vb + (it * 256 + (tid & 192)) * 16);
        }
    }

    // ---- Q fragments (two 16-row halves) + in-register RoPE ----
    // Scale folds 1/sqrt(128) * log2(e): softmax runs in exp2 domain.
    const int sl = lane >> 4;
    f16x8 af[2][4];
#pragma unroll
    for (int m = 0; m < 2; ++m) {
        int srow = qt0 + w * 32 + m * 16 + (lane & 15);
        const _Float16* qrp = qkv + (size_t)(b * SEQ + srow) * NQKV + h * HDIM;
#pragma unroll
        for (int ks = 0; ks < 4; ++ks)
            af[m][ks] = *reinterpret_cast<const f16x8*>(qrp + (ks * 4 + sl) * 8);
        const float qsc = 0.12751741f;          // 2^-3.5 * log2(e)
#pragma unroll
        for (int ks = 0; ks < 2; ++ks) {
            int d0 = (ks * 4 + sl) * 8;
            float cc[8], ss[8];
            *reinterpret_cast<float4*>(&cc[0]) = *reinterpret_cast<const float4*>(cos_t + srow * 64 + d0);
            *reinterpret_cast<float4*>(&cc[4]) = *reinterpret_cast<const float4*>(cos_t + srow * 64 + d0 + 4);
            *reinterpret_cast<float4*>(&ss[0]) = *reinterpret_cast<const float4*>(sin_t + srow * 64 + d0);
            *reinterpret_cast<float4*>(&ss[4]) = *reinterpret_cast<const float4*>(sin_t + srow * 64 + d0 + 4);
#pragma unroll
            for (int j = 0; j < 8; ++j) {
                float f1 = (float)af[m][ks][j], f2 = (float)af[m][ks + 2][j];
                af[m][ks][j]     = (_Float16)((f1 * cc[j] - f2 * ss[j]) * qsc);
                af[m][ks + 2][j] = (_Float16)((f2 * cc[j] + f1 * ss[j]) * qsc);
            }
        }
    }

    float m_run[2][4], l_run[2][4];
#pragma unroll
    for (int m = 0; m < 2; ++m)
#pragma unroll
        for (int r = 0; r < 4; ++r) { m_run[m][r] = -1e30f; l_run[m][r] = 0.f; }
    const f32x4 fz = {0.f, 0.f, 0.f, 0.f};
    f32x4 oacc[2][8];
#pragma unroll
    for (int m = 0; m < 2; ++m)
#pragma unroll
        for (int i = 0; i < 8; ++i) oacc[m][i] = fz;

    char* Pw = smem + 65536 + w * 4096;     // [32 rows][128 B] per wave
    const int prow = lane & 15;

    int cur = 0;
    for (int t = 0; t < SEQ / 64; ++t) {
        char* Kb = smem + (cur << 15);
        char* Vb = Kb + 16384;
        if (t < SEQ / 64 - 1) {
            char* Kn = smem + ((cur ^ 1) << 15);
            char* Vn = Kn + 16384;
            int t0n = (t + 1) << 6;
#pragma unroll
            for (int it = 0; it < 4; ++it) {
                int c = it * 256 + tid;
                int row = c >> 4, jc = c & 15;
                int sj = jc ^ (row & 7);
                glds16((const char*)(kbase + (size_t)(t0n + row) * HDIM) + (sj << 4),
                       Kn + (it * 256 + (tid & 192)) * 16);
            }
#pragma unroll
            for (int it = 0; it < 4; ++it) {
                int c = it * 256 + tid;
                int d = c >> 3, jc = c & 7;
                int sj = jc ^ (d & 7);
                glds16((const char*)(vbase + (size_t)d * SEQ + t0n) + (sj << 4),
                       Vn + (it * 256 + (tid & 192)) * 16);
            }
            asm volatile("s_waitcnt vmcnt(8)" ::: "memory");
        } else {
            asm volatile("s_waitcnt vmcnt(0)" ::: "memory");
        }
        asm volatile("s_barrier" ::: "memory");

        // ---- S = Q K^T (K fragment reused for both q-halves) ----
        f32x4 sacc[2][4];
#pragma unroll
        for (int m = 0; m < 2; ++m)
#pragma unroll
            for (int i = 0; i < 4; ++i) sacc[m][i] = fz;
#pragma unroll
        for (int ks = 0; ks < 4; ++ks) {
#pragma unroll
            for (int nf = 0; nf < 4; ++nf) {
                int trow = nf * 16 + (lane & 15);
                f16x8 bf = *reinterpret_cast<const f16x8*>(
                    Kb + trow * 256 + (((ks * 4 + (lane >> 4)) ^ (trow & 7)) << 4));
                sacc[0][nf] = __builtin_amdgcn_mfma_f32_16x16x32_f16(af[0][ks], bf, sacc[0][nf], 0, 0, 0);
                sacc[1][nf] = __builtin_amdgcn_mfma_f32_16x16x32_f16(af[1][ks], bf, sacc[1][nf], 0, 0, 0);
            }
        }

        // ---- online softmax (exp2 domain, DPP reduce, defer-max) ----
        float pm[2][4];
        float growth = -1e30f;
#pragma unroll
        for (int m = 0; m < 2; ++m)
#pragma unroll
            for (int r = 0; r < 4; ++r) {
                float v = fmaxf(fmaxf(sacc[m][0][r], sacc[m][1][r]),
                                fmaxf(sacc[m][2][r], sacc[m][3][r]));
                v = red16_max(v);
                pm[m][r] = v;
                growth = fmaxf(growth, v - m_run[m][r]);
            }
        if (__any(growth > 11.0f)) {            // 11 log2-units ~ e^7.6
            float scl[2][4];
#pragma unroll
            for (int m = 0; m < 2; ++m)
#pragma unroll
                for (int r = 0; r < 4; ++r) {
                    float mn = fmaxf(m_run[m][r], pm[m][r]);
                    scl[m][r] = __builtin_amdgcn_exp2f(m_run[m][r] - mn);
                    m_run[m][r] = mn;
                    l_run[m][r] *= scl[m][r];
                }
#pragma unroll
            for (int m = 0; m < 2; ++m)
#pragma unroll
                for (int i = 0; i < 8; ++i) {
                    f32x4 o = oacc[m][i];
                    o[0] *= scl[m][0]; o[1] *= scl[m][1];
                    o[2] *= scl[m][2]; o[3] *= scl[m][3];
                    oacc[m][i] = o;
                }
        }
#pragma unroll
        for (int m = 0; m < 2; ++m)
#pragma unroll
            for (int r = 0; r < 4; ++r) {
                float ps = 0.f;
#pragma unroll
                for (int nf = 0; nf < 4; ++nf) {
                    float p = __builtin_amdgcn_exp2f(sacc[m][nf][r] - m_run[m][r]);
                    sacc[m][nf][r] = p;
                    ps += p;
                }
                l_run[m][r] += ps;              // per-lane partial; epilogue reduce
            }

        // ---- P -> wave-private swizzled LDS (fp16) ----
#pragma unroll
        for (int m = 0; m < 2; ++m)
#pragma unroll
            for (int nf = 0; nf < 4; ++nf)
#pragma unroll
                for (int r = 0; r < 4; ++r) {
                    int pr = m * 16 + ((lane >> 4) << 2) + r;
                    int pc = nf * 16 + (lane & 15);
                    int byte = pr * 128 + ((pc * 2) ^ ((pr & 7) << 4));
                    *reinterpret_cast<_Float16*>(Pw + byte) = (_Float16)sacc[m][nf][r];
                }

        // ---- O += P V (V fragment reused for both q-halves) ----
#pragma unroll
        for (int ks = 0; ks < 2; ++ks) {
            int chP = ks * 4 + (lane >> 4);
            f16x8 pa[2];
#pragma unroll
            for (int m = 0; m < 2; ++m)
                pa[m] = *reinterpret_cast<const f16x8*>(
                    Pw + (m * 16 + prow) * 128 + ((chP ^ (prow & 7)) << 4));
#pragma unroll
            for (int nf = 0; nf < 8; ++nf) {
                int vrow = nf * 16 + (lane & 15);
                f16x8 vf = *reinterpret_cast<const f16x8*>(
                    Vb + vrow * 128 + (((ks * 4 + (lane >> 4)) ^ (vrow & 7)) << 4));
                oacc[0][nf] = __builtin_amdgcn_mfma_f32_16x16x32_f16(pa[0], vf, oacc[0][nf], 0, 0, 0);
                oacc[1][nf] = __builtin_amdgcn_mfma_f32_16x16x32_f16(pa[1], vf, oacc[1][nf], 0, 0, 0);
            }
        }

        asm volatile("s_barrier" ::: "memory");
        cur ^= 1;
    }

    // ---- epilogue: reduce l, normalize, write fp16 ----
    float linv[2][4];
#pragma unroll
    for (int m = 0; m < 2; ++m)
#pragma unroll
        for (int r = 0; r < 4; ++r)
            linv[m][r] = 1.0f / red16_sum(l_run[m][r]);
#pragma unroll
    for (int m = 0; m < 2; ++m)
#pragma unroll
        for (int nf = 0; nf < 8; ++nf)
#pragma unroll
            for (int r = 0; r < 4; ++r) {
                int qr  = qt0 + w * 32 + m * 16 + ((lane >> 4) << 2) + r;
                int col = h * HDIM + nf * 16 + (lane & 15);
                float v = oacc[m][nf][r] * linv[m][r];
                ao[(size_t)(b * SEQ + qr) * DMODEL + col] = (_Float16)v;
            }
}

// ---------------------------------------------------------------------------
extern "C" void kernel_launch(void* const* d_in, const int* in_sizes, int n_in,
                              void* d_out, int out_size, void* d_ws, size_t ws_size,
                              hipStream_t stream) {
    const float* x  = (const float*)d_in[0];
    const float* Wq = (const float*)d_in[1];
    const float* bq = (const float*)d_in[2];
    const float* Wk = (const float*)d_in[3];
    const float* bk = (const float*)d_in[4];
    const float* Wv = (const float*)d_in[5];
    const float* bv = (const float*)d_in[6];
    const float* Wo = (const float*)d_in[7];
    const float* bo = (const float*)d_in[8];
    float* out = (float*)d_out;

    char* ws = (char*)d_ws;
    _Float16* xs     = (_Float16*)(ws);                    // 16.78 MB [4096][2048]
    _Float16* wqkv16 = (_Float16*)(ws + 16777216);         // 10.49 MB [2560][2048]
    _Float16* wot16  = (_Float16*)(ws + 27262976);         //  8.39 MB [2048][2048]
    _Float16* qkv16  = (_Float16*)(ws + 35651584);         // 20.97 MB [4096][2560]
    _Float16* khb    = (_Float16*)(ws + 56623104);         //  2.10 MB [B][G][S][D]
    _Float16* vtb    = (_Float16*)(ws + 58720256);         //  2.10 MB [B][G][D][S]
    float*    sint   = (float*)(ws + 60817408);            //  0.26 MB
    float*    cost   = (float*)(ws + 61079552);            //  0.26 MB
    float*    bias_c = (float*)(ws + 61341696);            //  10 KB
    _Float16* ao = xs;   // attention output reuses xs (x dead after QKV GEMM)

    prep_const_kernel<<<266, 256, 0, stream>>>(sint, cost, bq, bk, bv, bias_c);
    convert_x_kernel<<<ROWS * DMODEL / 8 / 256, 256, 0, stream>>>(x, xs);
    transpose_w_all_kernel<<<dim3(72, 32), 256, 0, stream>>>(Wq, Wk, Wv, Wo, wqkv16, wot16);

    // QKV projection: [4096][2048] @ [2048][2560] -> fp16 [4096][2560]
    gemm_fp16_kernel<1><<<(ROWS / 128) * (NQKV / 128), 256, 0, stream>>>(
        xs, wqkv16, bias_c, qkv16, ROWS, NQKV, DMODEL);

    prep_kv_kernel<<<dim3(SEQ / 64, BATCH * NGROUPS), 256, 0, stream>>>(
        qkv16, sint, cost, khb, vtb);

    attn_kernel<<<dim3(SEQ / 128, NHEADS, BATCH), 256, 0, stream>>>(
        qkv16, khb, vtb, sint, cost, ao);

    // Output projection: [4096][2048] @ [2048][2048] -> fp32 out
    gemm_fp16_kernel<0><<<(ROWS / 128) * (DMODEL / 128), 256, 0, stream>>>(
        ao, wot16, bo, out, ROWS, DMODEL, DMODEL);
}

// Round 10
// 266.204 us; speedup vs baseline: 1.2814x; 1.0030x over previous
//
#include <hip/hip_runtime.h>
#include <hip/hip_bf16.h>
#include <hip/hip_fp16.h>
#include <math.h>

#define BATCH   4
#define SEQ     1024
#define DMODEL  2048
#define NHEADS  16
#define NGROUPS 2
#define HDIM    128
#define ROWS    (BATCH * SEQ)      // 4096
#define NQKV    2560               // 2048 q + 256 k + 256 v

typedef float    f32x4 __attribute__((ext_vector_type(4)));
typedef _Float16 f16x8 __attribute__((ext_vector_type(8)));
typedef _Float16 f16x4 __attribute__((ext_vector_type(4)));

__device__ __forceinline__ void glds16(const void* g, void* s) {
    __builtin_amdgcn_global_load_lds(
        (__attribute__((address_space(1))) void*)g,
        (__attribute__((address_space(3))) void*)s, 16, 0, 0);
}

// ---------------------------------------------------------------------------
// Fused prep: convert_x (blocks 0..4095) + W transposes (4096..6399) +
// RoPE tables / bias concat (6400..6665).
// ---------------------------------------------------------------------------
__global__ __launch_bounds__(256)
void prep_all_kernel(const float* __restrict__ x, _Float16* __restrict__ xo,
                     const float* __restrict__ Wq, const float* __restrict__ Wk,
                     const float* __restrict__ Wv, const float* __restrict__ Wo,
                     _Float16* __restrict__ wqkv, _Float16* __restrict__ wot,
                     float* __restrict__ sin_t, float* __restrict__ cos_t,
                     const float* __restrict__ bq, const float* __restrict__ bk,
                     const float* __restrict__ bv, float* __restrict__ bc) {
    __shared__ float tile[64][65];
    int bid = blockIdx.x;
    if (bid < 4096) {
        int i = (bid * 256 + threadIdx.x) * 8;
        float v[8];
        *reinterpret_cast<float4*>(&v[0]) = *reinterpret_cast<const float4*>(x + i);
        *reinterpret_cast<float4*>(&v[4]) = *reinterpret_cast<const float4*>(x + i + 4);
        f16x8 h;
#pragma unroll
        for (int j = 0; j < 8; ++j) h[j] = (_Float16)v[j];
        *reinterpret_cast<f16x8*>(xo + i) = h;
    } else if (bid < 6400) {
        int tb = bid - 4096;
        int bx = tb % 72, by = tb / 72;
        const float* W; int ldw, drow0, nb; _Float16* dst;
        if (bx < 32)      { W = Wq; ldw = DMODEL; dst = wqkv; drow0 = 0;    nb = bx; }
        else if (bx < 36) { W = Wk; ldw = 256;    dst = wqkv; drow0 = 2048; nb = bx - 32; }
        else if (bx < 40) { W = Wv; ldw = 256;    dst = wqkv; drow0 = 2304; nb = bx - 36; }
        else              { W = Wo; ldw = DMODEL; dst = wot;  drow0 = 0;    nb = bx - 40; }
        int n0 = nb * 64, k0 = by * 64;
#pragma unroll
        for (int it = 0; it < 16; ++it) {
            int e = it * 256 + threadIdx.x;
            int r = e >> 6, c = e & 63;
            tile[r][c] = W[(size_t)(k0 + r) * ldw + n0 + c];
        }
        __syncthreads();
#pragma unroll
        for (int it = 0; it < 16; ++it) {
            int e = it * 256 + threadIdx.x;
            int nr = e >> 6, kc = e & 63;
            dst[(size_t)(drow0 + n0 + nr) * DMODEL + k0 + kc] = (_Float16)tile[kc][nr];
        }
    } else {
        int b2 = bid - 6400;
        if (b2 < 256) {
            int idx = b2 * 256 + threadIdx.x;
            int p = idx >> 6, j = idx & 63;
            float inv = powf(10000.0f, -(float)j * (1.0f / 64.0f));
            float f = (float)p * inv;
            sin_t[idx] = sinf(f);
            cos_t[idx] = cosf(f);
        } else {
            int i = (b2 - 256) * 256 + threadIdx.x;
            if (i < NQKV)
                bc[i] = (i < 2048) ? bq[i] : ((i < 2304) ? bk[i - 2048] : bv[i - 2304]);
        }
    }
}

// ---------------------------------------------------------------------------
// fp16 GEMM: C[M][N] = A[M][K] @ Bt^T[N][K] + bias.  (unchanged)
// ---------------------------------------------------------------------------
template<int OUT_HALF>
__global__ __launch_bounds__(256, 3)
void gemm_fp16_kernel(const _Float16* __restrict__ A, const _Float16* __restrict__ Bt,
                      const float* __restrict__ bias, void* __restrict__ Cout,
                      int M, int N, int K) {
    __shared__ __align__(16) _Float16 lds[16384];   // 32 KB: A [128][64], B [128][64]
    _Float16* As = lds;
    _Float16* Bs = lds + 8192;

    const int tid  = threadIdx.x;
    const int lane = tid & 63;
    const int w    = tid >> 6;
    const int nbn  = N >> 7;
    const int nwg  = gridDim.x;
    const int cpx  = nwg >> 3;
    const int bid  = blockIdx.x;
    const int swz  = (bid & 7) * cpx + (bid >> 3);
    const int row0 = (swz / nbn) << 7;
    const int col0 = (swz % nbn) << 7;
    const int wr   = (w >> 1) << 6;
    const int wc   = (w & 1) << 6;

    const f32x4 fz = {0.f, 0.f, 0.f, 0.f};
    f32x4 acc[4][4];
#pragma unroll
    for (int i = 0; i < 4; ++i)
#pragma unroll
        for (int j = 0; j < 4; ++j) acc[i][j] = fz;

    for (int k0 = 0; k0 < K; k0 += 64) {
        __syncthreads();
#pragma unroll
        for (int it = 0; it < 4; ++it) {
            int chunk = it * 256 + tid;
            int trow  = chunk >> 3;
            int jp    = chunk & 7;
            int j     = jp ^ (trow & 7);
            size_t aoff = (size_t)(row0 + trow) * K + k0 + j * 8;
            size_t boff = (size_t)(col0 + trow) * K + k0 + j * 8;
            int ldst = (it * 256 + (tid & 192)) * 16;
            glds16(A  + aoff, (char*)As + ldst);
            glds16(Bt + boff, (char*)Bs + ldst);
        }
        __syncthreads();

#pragma unroll
        for (int ks = 0; ks < 2; ++ks) {
            f16x8 a4[4], b4[4];
            int ja = ks * 4 + (lane >> 4);
#pragma unroll
            for (int i = 0; i < 4; ++i) {
                int ar = wr + i * 16 + (lane & 15);
                a4[i] = *reinterpret_cast<const f16x8*>(
                    (const char*)As + ar * 128 + ((ja ^ (ar & 7)) << 4));
                int br = wc + i * 16 + (lane & 15);
                b4[i] = *reinterpret_cast<const f16x8*>(
                    (const char*)Bs + br * 128 + ((ja ^ (br & 7)) << 4));
            }
#pragma unroll
            for (int i = 0; i < 4; ++i)
#pragma unroll
                for (int j = 0; j < 4; ++j)
                    acc[i][j] = __builtin_amdgcn_mfma_f32_16x16x32_f16(a4[i], b4[j], acc[i][j], 0, 0, 0);
        }
    }

    float bv4[4];
#pragma unroll
    for (int j = 0; j < 4; ++j) bv4[j] = bias[col0 + wc + j * 16 + (lane & 15)];
#pragma unroll
    for (int i = 0; i < 4; ++i)
#pragma unroll
        for (int j = 0; j < 4; ++j)
#pragma unroll
            for (int r = 0; r < 4; ++r) {
                int grow = row0 + wr + i * 16 + ((lane >> 4) << 2) + r;
                int gcol = col0 + wc + j * 16 + (lane & 15);
                float v = acc[i][j][r] + bv4[j];
                if (OUT_HALF)
                    ((_Float16*)Cout)[(size_t)grow * N + gcol] = (_Float16)v;
                else
                    ((float*)Cout)[(size_t)grow * N + gcol] = v;
            }
}

// ---------------------------------------------------------------------------
// Fused K-RoPE + V-transpose. Grid (SEQ/64, BATCH*NGROUPS), 256 thr.
// ---------------------------------------------------------------------------
__global__ __launch_bounds__(256)
void prep_kv_kernel(const _Float16* __restrict__ qkv,
                    const float* __restrict__ sin_t, const float* __restrict__ cos_t,
                    _Float16* __restrict__ kh, _Float16* __restrict__ vt) {
    __shared__ _Float16 tile[64][72];
    int s0 = blockIdx.x * 64, bg = blockIdx.y;
    int b = bg >> 1, g = bg & 1;

#pragma unroll
    for (int it = 0; it < 2; ++it) {
        int u = it * 256 + threadIdx.x;
        int r = u >> 3, jc = u & 7;
        int s = s0 + r;
        int j0 = jc * 8;
        const _Float16* src = qkv + (size_t)(b * SEQ + s) * NQKV + 2048 + g * HDIM;
        _Float16* dst = kh + ((size_t)bg * SEQ + s) * HDIM;
        f16x8 x1 = *reinterpret_cast<const f16x8*>(src + j0);
        f16x8 x2 = *reinterpret_cast<const f16x8*>(src + j0 + 64);
        float cc[8], ss[8];
        *reinterpret_cast<float4*>(&cc[0]) = *reinterpret_cast<const float4*>(cos_t + s * 64 + j0);
        *reinterpret_cast<float4*>(&cc[4]) = *reinterpret_cast<const float4*>(cos_t + s * 64 + j0 + 4);
        *reinterpret_cast<float4*>(&ss[0]) = *reinterpret_cast<const float4*>(sin_t + s * 64 + j0);
        *reinterpret_cast<float4*>(&ss[4]) = *reinterpret_cast<const float4*>(sin_t + s * 64 + j0 + 4);
        f16x8 o1, o2;
#pragma unroll
        for (int j = 0; j < 8; ++j) {
            float f1 = (float)x1[j], f2 = (float)x2[j];
            o1[j] = (_Float16)(f1 * cc[j] - f2 * ss[j]);
            o2[j] = (_Float16)(f2 * cc[j] + f1 * ss[j]);
        }
        *reinterpret_cast<f16x8*>(dst + j0)      = o1;
        *reinterpret_cast<f16x8*>(dst + j0 + 64) = o2;
    }

#pragma unroll
    for (int half = 0; half < 2; ++half) {
        int d0 = half * 64;
        __syncthreads();
#pragma unroll
        for (int it = 0; it < 2; ++it) {
            int c = it * 256 + threadIdx.x;
            int r = c >> 3, cc = (c & 7) * 8;
            f16x8 v = *reinterpret_cast<const f16x8*>(
                qkv + (size_t)(b * SEQ + s0 + r) * NQKV + 2304 + g * HDIM + d0 + cc);
#pragma unroll
            for (int j = 0; j < 8; ++j) tile[r][cc + j] = v[j];
        }
        __syncthreads();
#pragma unroll
        for (int it = 0; it < 2; ++it) {
            int c = it * 256 + threadIdx.x;
            int dr = c >> 3, sc = (c & 7) * 8;
            f16x8 o;
#pragma unroll
            for (int j = 0; j < 8; ++j) o[j] = tile[sc + j][dr];
            *reinterpret_cast<f16x8*>(vt + ((size_t)bg * HDIM + d0 + dr) * SEQ + s0 + sc) = o;
        }
    }
}

// ---------------------------------------------------------------------------
// Flash attention, fp16 MFMA. Grid (SEQ/128, NHEADS, BATCH), 256 thr (4 waves).
// K/V double-buffered, counted vmcnt(8). Wave owns 32 q-rows.
// SWAPPED QK^T: S^T = mfma(K, Q) -> lane's q = lane&15, P-row lane-local:
// in-lane row-max (15 fmax + 2 shuffles), P -> LDS via 8x ds_write_b64
// (verified to tile the PV A-fragment b128 reads under the same XOR swizzle).
// exp2-domain softmax; per-lane deferred l-sum; bpermute redistribution only
// in the rare rescale branch and once in the epilogue.
// ---------------------------------------------------------------------------
__global__ __launch_bounds__(256, 2)
void attn_kernel(const _Float16* __restrict__ qkv, const _Float16* __restrict__ kh,
                 const _Float16* __restrict__ vt,
                 const float* __restrict__ sin_t, const float* __restrict__ cos_t,
                 _Float16* __restrict__ ao) {
    __shared__ __align__(16) char smem[81920];
    // [0,16K) K0 | [16K,32K) V0 | [32K,48K) K1 | [48K,64K) V1 | [64K,80K) P

    const int tid = threadIdx.x, lane = tid & 63, w = tid >> 6;
    const int qv  = lane & 15;              // this lane's q (S^T col) / P row
    const int grp = lane >> 4;              // 16-lane group id
    const int qt0 = blockIdx.x << 7;        // 128 q rows per block
    const int h = blockIdx.y, b = blockIdx.z;
    const int g = h >> 3;
    const _Float16* kbase = kh + (size_t)(b * NGROUPS + g) * SEQ * HDIM;
    const _Float16* vbase = vt + (size_t)(b * NGROUPS + g) * HDIM * SEQ;

    // ---- stage K/V tile 0 into buffer 0 ----
    {
        char* Kb = smem;
        char* Vb = smem + 16384;
#pragma unroll
        for (int it = 0; it < 4; ++it) {
            int c = it * 256 + tid;
            int row = c >> 4, jc = c & 15;
            int sj = jc ^ (row & 7);
            glds16((const char*)(kbase + (size_t)row * HDIM) + (sj << 4),
                   Kb + (it * 256 + (tid & 192)) * 16);
        }
#pragma unroll
        for (int it = 0; it < 4; ++it) {
            int c = it * 256 + tid;
            int d = c >> 3, jc = c & 7;
            int sj = jc ^ (d & 7);
            glds16((const char*)(vbase + (size_t)d * SEQ) + (sj << 4),
                   Vb + (it * 256 + (tid & 192)) * 16);
        }
    }

    // ---- Q fragments (two 16-row halves) + in-register RoPE ----
    // Scale folds 1/sqrt(128) * log2(e): softmax runs in exp2 domain.
    f16x8 af[2][4];
#pragma unroll
    for (int m = 0; m < 2; ++m) {
        int srow = qt0 + w * 32 + m * 16 + qv;
        const _Float16* qrp = qkv + (size_t)(b * SEQ + srow) * NQKV + h * HDIM;
#pragma unroll
        for (int ks = 0; ks < 4; ++ks)
            af[m][ks] = *reinterpret_cast<const f16x8*>(qrp + (ks * 4 + grp) * 8);
        const float qsc = 0.12751741f;      // 2^-3.5 * log2(e)
#pragma unroll
        for (int ks = 0; ks < 2; ++ks) {
            int d0 = (ks * 4 + grp) * 8;
            float cc[8], ss[8];
            *reinterpret_cast<float4*>(&cc[0]) = *reinterpret_cast<const float4*>(cos_t + srow * 64 + d0);
            *reinterpret_cast<float4*>(&cc[4]) = *reinterpret_cast<const float4*>(cos_t + srow * 64 + d0 + 4);
            *reinterpret_cast<float4*>(&ss[0]) = *reinterpret_cast<const float4*>(sin_t + srow * 64 + d0);
            *reinterpret_cast<float4*>(&ss[4]) = *reinterpret_cast<const float4*>(sin_t + srow * 64 + d0 + 4);
#pragma unroll
            for (int j = 0; j < 8; ++j) {
                float f1 = (float)af[m][ks][j], f2 = (float)af[m][ks + 2][j];
                af[m][ks][j]     = (_Float16)((f1 * cc[j] - f2 * ss[j]) * qsc);
                af[m][ks + 2][j] = (_Float16)((f2 * cc[j] + f1 * ss[j]) * qsc);
            }
        }
    }

    float m_run[2] = {-1e30f, -1e30f};      // per-lane: q = qv (both m halves)
    float l_run[2] = {0.f, 0.f};
    const f32x4 fz = {0.f, 0.f, 0.f, 0.f};
    f32x4 oacc[2][8];
#pragma unroll
    for (int m = 0; m < 2; ++m)
#pragma unroll
        for (int i = 0; i < 8; ++i) oacc[m][i] = fz;

    char* Pw = smem + 65536 + w * 4096;     // per wave: 2 x [16 q][64 kv] f16

    int cur = 0;
    for (int t = 0; t < SEQ / 64; ++t) {
        char* Kb = smem + (cur << 15);
        char* Vb = Kb + 16384;
        if (t < SEQ / 64 - 1) {
            char* Kn = smem + ((cur ^ 1) << 15);
            char* Vn = Kn + 16384;
            int t0n = (t + 1) << 6;
#pragma unroll
            for (int it = 0; it < 4; ++it) {
                int c = it * 256 + tid;
                int row = c >> 4, jc = c & 15;
                int sj = jc ^ (row & 7);
                glds16((const char*)(kbase + (size_t)(t0n + row) * HDIM) + (sj << 4),
                       Kn + (it * 256 + (tid & 192)) * 16);
            }
#pragma unroll
            for (int it = 0; it < 4; ++it) {
                int c = it * 256 + tid;
                int d = c >> 3, jc = c & 7;
                int sj = jc ^ (d & 7);
                glds16((const char*)(vbase + (size_t)d * SEQ + t0n) + (sj << 4),
                       Vn + (it * 256 + (tid & 192)) * 16);
            }
            asm volatile("s_waitcnt vmcnt(8)" ::: "memory");
        } else {
            asm volatile("s_waitcnt vmcnt(0)" ::: "memory");
        }
        asm volatile("s_barrier" ::: "memory");

        // ---- S^T = K Q^T : sacc[m][nf][r] = S[q=qv][kv=nf*16+grp*4+r] ----
        f32x4 sacc[2][4];
#pragma unroll
        for (int m = 0; m < 2; ++m)
#pragma unroll
            for (int i = 0; i < 4; ++i) sacc[m][i] = fz;
#pragma unroll
        for (int ks = 0; ks < 4; ++ks) {
#pragma unroll
            for (int nf = 0; nf < 4; ++nf) {
                int trow = nf * 16 + qv;
                f16x8 kf = *reinterpret_cast<const f16x8*>(
                    Kb + trow * 256 + (((ks * 4 + grp) ^ (trow & 7)) << 4));
                sacc[0][nf] = __builtin_amdgcn_mfma_f32_16x16x32_f16(kf, af[0][ks], sacc[0][nf], 0, 0, 0);
                sacc[1][nf] = __builtin_amdgcn_mfma_f32_16x16x32_f16(kf, af[1][ks], sacc[1][nf], 0, 0, 0);
            }
        }

        // ---- online softmax (in-lane row max; exp2 domain; defer-max) ----
        float pm2[2];
#pragma unroll
        for (int m = 0; m < 2; ++m) {
            float v = sacc[m][0][0];
#pragma unroll
            for (int nf = 0; nf < 4; ++nf)
#pragma unroll
                for (int r = 0; r < 4; ++r) v = fmaxf(v, sacc[m][nf][r]);
            v = fmaxf(v, __shfl_xor(v, 16));
            v = fmaxf(v, __shfl_xor(v, 32));
            pm2[m] = v;
        }
        float growth = fmaxf(pm2[0] - m_run[0], pm2[1] - m_run[1]);
        if (__any(growth > 11.0f)) {        // 11 log2-units ~ e^7.6
            float scl[2];
#pragma unroll
            for (int m = 0; m < 2; ++m) {
                float mn = fmaxf(m_run[m], pm2[m]);
                scl[m] = __builtin_amdgcn_exp2f(m_run[m] - mn);
                m_run[m] = mn;
                l_run[m] *= scl[m];
            }
            // redistribute scl (indexed by q=qv) to oacc layout (q=grp*4+r)
            float sclo[2][4];
#pragma unroll
            for (int m = 0; m < 2; ++m)
#pragma unroll
                for (int r = 0; r < 4; ++r)
                    sclo[m][r] = __int_as_float(__builtin_amdgcn_ds_bpermute(
                        ((grp << 2) + r) << 2, __float_as_int(scl[m])));
#pragma unroll
            for (int m = 0; m < 2; ++m)
#pragma unroll
                for (int i = 0; i < 8; ++i) {
                    f32x4 o = oacc[m][i];
                    o[0] *= sclo[m][0]; o[1] *= sclo[m][1];
                    o[2] *= sclo[m][2]; o[3] *= sclo[m][3];
                    oacc[m][i] = o;
                }
        }
#pragma unroll
        for (int m = 0; m < 2; ++m) {
            float ps = 0.f;
#pragma unroll
            for (int nf = 0; nf < 4; ++nf)
#pragma unroll
                for (int r = 0; r < 4; ++r) {
                    float p = __builtin_amdgcn_exp2f(sacc[m][nf][r] - m_run[m]);
                    sacc[m][nf][r] = p;
                    ps += p;
                }
            l_run[m] += ps;                 // per-lane partial; epilogue reduce
        }

        // ---- P -> LDS: [16 q][64 kv] per (wave, m), 4-contig kv per write ----
#pragma unroll
        for (int m = 0; m < 2; ++m)
#pragma unroll
            for (int nf = 0; nf < 4; ++nf) {
                f16x4 pk;
#pragma unroll
                for (int r = 0; r < 4; ++r) pk[r] = (_Float16)sacc[m][nf][r];
                int byte = m * 2048 + qv * 128 + nf * 32 + grp * 8;
                byte ^= (qv & 7) << 4;
                *reinterpret_cast<f16x4*>(Pw + byte) = pk;
            }

        // ---- O += P V (V fragment reused for both q-halves) ----
#pragma unroll
        for (int ks = 0; ks < 2; ++ks) {
            f16x8 pa[2];
#pragma unroll
            for (int m = 0; m < 2; ++m) {
                int byte = m * 2048 + qv * 128 + ks * 64 + grp * 16;
                byte ^= (qv & 7) << 4;
                pa[m] = *reinterpret_cast<const f16x8*>(Pw + byte);
            }
#pragma unroll
            for (int nf = 0; nf < 8; ++nf) {
                int vrow = nf * 16 + qv;
                f16x8 vf = *reinterpret_cast<const f16x8*>(
                    Vb + vrow * 128 + (((ks * 4 + grp) ^ (vrow & 7)) << 4));
                oacc[0][nf] = __builtin_amdgcn_mfma_f32_16x16x32_f16(pa[0], vf, oacc[0][nf], 0, 0, 0);
                oacc[1][nf] = __builtin_amdgcn_mfma_f32_16x16x32_f16(pa[1], vf, oacc[1][nf], 0, 0, 0);
            }
        }

        asm volatile("s_barrier" ::: "memory");
        cur ^= 1;
    }

    // ---- epilogue: reduce l (per q=qv), redistribute, normalize, write ----
    float linvo[2][4];
#pragma unroll
    for (int m = 0; m < 2; ++m) {
        float ls = l_run[m];
        ls += __shfl_xor(ls, 16);
        ls += __shfl_xor(ls, 32);
        float linv = 1.0f / ls;
#pragma unroll
        for (int r = 0; r < 4; ++r)
            linvo[m][r] = __int_as_float(__builtin_amdgcn_ds_bpermute(
                ((grp << 2) + r) << 2, __float_as_int(linv)));
    }
#pragma unroll
    for (int m = 0; m < 2; ++m)
#pragma unroll
        for (int nf = 0; nf < 8; ++nf)
#pragma unroll
            for (int r = 0; r < 4; ++r) {
                int qr  = qt0 + w * 32 + m * 16 + (grp << 2) + r;
                int col = h * HDIM + nf * 16 + qv;
                float v = oacc[m][nf][r] * linvo[m][r];
                ao[(size_t)(b * SEQ + qr) * DMODEL + col] = (_Float16)v;
            }
}

// ---------------------------------------------------------------------------
extern "C" void kernel_launch(void* const* d_in, const int* in_sizes, int n_in,
                              void* d_out, int out_size, void* d_ws, size_t ws_size,
                              hipStream_t stream) {
    const float* x  = (const float*)d_in[0];
    const float* Wq = (const float*)d_in[1];
    const float* bq = (const float*)d_in[2];
    const float* Wk = (const float*)d_in[3];
    const float* bk = (const float*)d_in[4];
    const float* Wv = (const float*)d_in[5];
    const float* bv = (const float*)d_in[6];
    const float* Wo = (const float*)d_in[7];
    const float* bo = (const float*)d_in[8];
    float* out = (float*)d_out;

    char* ws = (char*)d_ws;
    _Float16* xs     = (_Float16*)(ws);                    // 16.78 MB [4096][2048]
    _Float16* wqkv16 = (_Float16*)(ws + 16777216);         // 10.49 MB [2560][2048]
    _Float16* wot16  = (_Float16*)(ws + 27262976);         //  8.39 MB [2048][2048]
    _Float16* qkv16  = (_Float16*)(ws + 35651584);         // 20.97 MB [4096][2560]
    _Float16* khb    = (_Float16*)(ws + 56623104);         //  2.10 MB [B][G][S][D]
    _Float16* vtb    = (_Float16*)(ws + 58720256);         //  2.10 MB [B][G][D][S]
    float*    sint   = (float*)(ws + 60817408);            //  0.26 MB
    float*    cost   = (float*)(ws + 61079552);            //  0.26 MB
    float*    bias_c = (float*)(ws + 61341696);            //  10 KB
    _Float16* ao = xs;   // attention output reuses xs (x dead after QKV GEMM)

    prep_all_kernel<<<6666, 256, 0, stream>>>(x, xs, Wq, Wk, Wv, Wo,
                                              wqkv16, wot16, sint, cost,
                                              bq, bk, bv, bias_c);

    // QKV projection: [4096][2048] @ [2048][2560] -> fp16 [4096][2560]
    gemm_fp16_kernel<1><<<(ROWS / 128) * (NQKV / 128), 256, 0, stream>>>(
        xs, wqkv16, bias_c, qkv16, ROWS, NQKV, DMODEL);

    prep_kv_kernel<<<dim3(SEQ / 64, BATCH * NGROUPS), 256, 0, stream>>>(
        qkv16, sint, cost, khb, vtb);

    attn_kernel<<<dim3(SEQ / 128, NHEADS, BATCH), 256, 0, stream>>>(
        qkv16, khb, vtb, sint, cost, ao);

    // Output projection: [4096][2048] @ [2048][2048] -> fp32 out
    gemm_fp16_kernel<0><<<(ROWS / 128) * (DMODEL / 128), 256, 0, stream>>>(
        ao, wot16, bo, out, ROWS, DMODEL, DMODEL);
}